// Round 5
// baseline (81.795 us; speedup 1.0000x reference)
//
#include <hip/hip_runtime.h>
#include <hip/hip_bf16.h>

// Problem constants
#define BB     32
#define HIDD   128
#define ATT    128
#define SS     8192            // T*N positions per batch
#define CH     64              // rows per chunk
#define NCH    4               // chunks per block
#define BLKPB  (SS / (CH * NCH))   // 32 blocks per batch
#define PART_STRIDE 130        // [m, l, acc[128]]

typedef float f32x4 __attribute__((ext_vector_type(4)));
typedef short s16x8 __attribute__((ext_vector_type(8)));

__device__ inline unsigned short f2bf(float x) {
    unsigned u = __float_as_uint(x);
    u += 0x7FFFu + ((u >> 16) & 1u);   // RNE
    return (unsigned short)(u >> 16);
}
__device__ inline float bf2f(unsigned short h) {
    return __uint_as_float(((unsigned)h) << 16);
}
__device__ inline float fast_tanh(float x) {
    x = fminf(15.f, fmaxf(-15.f, x));
    float e2 = __expf(2.f * x);
    return (e2 - 1.f) * __builtin_amdgcn_rcpf(e2 + 1.f);
}
__device__ inline unsigned cvt_pk_bf16(float a, float b) {
    unsigned r;
    asm("v_cvt_pk_bf16_f32 %0, %1, %2" : "=v"(r) : "v"(a), "v"(b));
    return r;   // low16 = bf16(a), high16 = bf16(b)
}
// raw barrier: LDS visibility only — vmem loads stay in flight across it
__device__ inline void lgk0_barrier() {
    __builtin_amdgcn_sched_barrier(0);
    asm volatile("s_waitcnt lgkmcnt(0)" ::: "memory");
    __builtin_amdgcn_s_barrier();
    __builtin_amdgcn_sched_barrier(0);
}

// ---- prep (merged): blocks 0..63 -> Wh_w f32->bf16; blocks 64..95 -> bias2 ----
__global__ void prep_kernel(const float* __restrict__ whw,
                            unsigned short* __restrict__ wbf,
                            const float* __restrict__ cur,
                            const float* __restrict__ wxw,
                            const float* __restrict__ wxb,
                            const float* __restrict__ whb,
                            float* __restrict__ bias2) {
    if (blockIdx.x < 64) {
        int i = blockIdx.x * 256 + threadIdx.x;   // 16384 total
        wbf[i] = f2bf(whw[i]);
    } else {
        __shared__ float sc[HIDD];
        int b = blockIdx.x - 64;
        int a = threadIdx.x;
        if (a < HIDD) sc[a] = cur[b * HIDD + a];
        __syncthreads();
        if (a < ATT) {
            float d = 0.f;
#pragma unroll 8
            for (int h = 0; h < HIDD; ++h) d += sc[h] * wxw[a * HIDD + h];
            bias2[b * ATT + a] = d + wxb[a] + whb[a];
        }
    }
}

// ---- main: per block: 4 chunks of 64 rows. Reg-staged async pipeline:
//      loads for chunk c+1 in VGPRs while chunk c computes (bf16 LDS,
//      double-buffered halves). Swapped MFMA + in-lane v-dot. Online softmax
//      + register accumulator across chunks. Raw barriers (no vmcnt drain). ----
__global__ __launch_bounds__(256, 4) void attn_main_kernel(
    const float* __restrict__ hist,
    const unsigned short* __restrict__ wbf,
    const float* __restrict__ bias2,
    const float* __restrict__ vw,
    float* __restrict__ partials)
{
    __shared__ __align__(16) unsigned short sH[2][CH * HIDD];  // 2 x 16 KB bf16, swizzled
    __shared__ float sScoreP[4][CH];                           // per-wave partial scores
    __shared__ float sAcc[8][HIDD];                            // 4 KB (epilogue only)

    const int tid  = threadIdx.x;
    const int bid  = blockIdx.x;
    const int b    = bid / BLKPB;
    const int blk  = bid % BLKPB;
    const int lane = tid & 63;
    const int wid  = tid >> 6;
    const int l15  = lane & 15;
    const int lg   = lane >> 4;
    const int sg   = tid >> 5;      // 0..7: row-group for accumulation
    const int hq   = tid & 31;      // h-quad column for accumulation

    // ---- this wave's 2 a-tiles: W fragments (A operand), bias, v in registers ----
    s16x8 wfrag[2][4];
    float bia[2][4], vv[2][4];
#pragma unroll
    for (int j = 0; j < 2; ++j) {
        int arow = (wid * 2 + j) * 16 + l15;
#pragma unroll
        for (int kk = 0; kk < 4; ++kk)
            wfrag[j][kk] = *(const s16x8*)(wbf + arow * HIDD + kk * 32 + lg * 8);
#pragma unroll
        for (int r = 0; r < 4; ++r) {
            int a = (wid * 2 + j) * 16 + lg * 4 + r;
            bia[j][r] = bias2[b * ATT + a];
            vv[j][r]  = vw[a];
        }
    }

    const float* src0 = hist + ((size_t)b * SS + (size_t)blk * CH * NCH) * HIDD;
    f32x4 vb[8];   // in-flight chunk (64x128 f32 / 256 threads = 8 f32x4)

    // issue global loads for chunk c into vb (pairs so writes are b128)
    auto stage_load = [&](int c) {
        const float* src = src0 + (size_t)c * CH * HIDD;
#pragma unroll
        for (int i = 0; i < 4; ++i) {
            int g0 = (i * 256 + tid) * 2;          // f32x4 unit index
            vb[2 * i]     = *(const f32x4*)(src + (size_t)g0 * 4);
            vb[2 * i + 1] = *(const f32x4*)(src + (size_t)g0 * 4 + 4);
        }
        __builtin_amdgcn_sched_barrier(0);         // don't sink loads past here
    };
    // cvt vb -> bf16, write swizzled into sH[buf]
    auto stage_write = [&](int buf) {
#pragma unroll
        for (int i = 0; i < 4; ++i) {
            int bu   = i * 256 + tid;              // ushort8 unit index
            int row  = bu >> 4;
            int ucol = bu & 15;
            union { s16x8 v; unsigned w[4]; } o;
            o.w[0] = cvt_pk_bf16(vb[2 * i].x,     vb[2 * i].y);
            o.w[1] = cvt_pk_bf16(vb[2 * i].z,     vb[2 * i].w);
            o.w[2] = cvt_pk_bf16(vb[2 * i + 1].x, vb[2 * i + 1].y);
            o.w[3] = cvt_pk_bf16(vb[2 * i + 1].z, vb[2 * i + 1].w);
            *(s16x8*)&sH[buf][(row * HIDD + ucol * 8) ^ ((row & 7) << 3)] = o.v;
        }
    };

    // ---- prologue: fill buf0, start chunk1 loads ----
    stage_load(0);
    stage_write(0);
    stage_load(1);
    lgk0_barrier();                                // A(0)

    float m_run = -1e30f, l_run = 0.f;
    f32x4 acc4 = {0.f, 0.f, 0.f, 0.f};

#pragma unroll
    for (int c = 0; c < NCH; ++c) {
        const int cur = c & 1;

        // ---- scores: 4 s-tiles, D[a][s] = W . H^T, v-dot in-lane ----
#pragma unroll
        for (int st = 0; st < 4; ++st) {
            int srow = st * 16 + l15;
            s16x8 hfrag[4];
#pragma unroll
            for (int kk = 0; kk < 4; ++kk) {
                int idx = (srow * HIDD + kk * 32 + lg * 8) ^ ((srow & 7) << 3);
                hfrag[kk] = *(const s16x8*)&sH[cur][idx];
            }
            f32x4 acc0 = {0.f, 0.f, 0.f, 0.f};
            f32x4 acc1 = {0.f, 0.f, 0.f, 0.f};
            __builtin_amdgcn_s_setprio(1);
#pragma unroll
            for (int kk = 0; kk < 4; ++kk) {
                acc0 = __builtin_amdgcn_mfma_f32_16x16x32_bf16(wfrag[0][kk], hfrag[kk], acc0, 0, 0, 0);
                acc1 = __builtin_amdgcn_mfma_f32_16x16x32_bf16(wfrag[1][kk], hfrag[kk], acc1, 0, 0, 0);
            }
            __builtin_amdgcn_s_setprio(0);
            float p = 0.f;
#pragma unroll
            for (int r = 0; r < 4; ++r)
                p += vv[0][r] * fast_tanh(acc0[r] + bia[0][r])
                   + vv[1][r] * fast_tanh(acc1[r] + bia[1][r]);
            p += __shfl_xor(p, 16, 64);
            p += __shfl_xor(p, 32, 64);
            if (lg == 0) sScoreP[wid][st * 16 + l15] = p;
        }
        lgk0_barrier();                            // B(c): sScoreP visible

        // ---- online softmax (every wave computes identical stats) ----
        float scv = sScoreP[0][lane] + sScoreP[1][lane] + sScoreP[2][lane] + sScoreP[3][lane];
        float mx = scv;
#pragma unroll
        for (int m = 1; m < 64; m <<= 1) mx = fmaxf(mx, __shfl_xor(mx, m, 64));
        float m_new = fmaxf(m_run, mx);
        float so = __expf(m_run - m_new);
        float ev = __expf(scv - m_new);            // lane holds e for row=lane
        float es = ev;
#pragma unroll
        for (int m = 1; m < 64; m <<= 1) es += __shfl_xor(es, m, 64);
        l_run = l_run * so + es;
        m_run = m_new;

        // ---- weighted accumulation from sH[cur] (bf16), register acc ----
        acc4 *= so;
#pragma unroll
        for (int r = 0; r < 8; ++r) {
            int row = (sg & 7) * 8 + r;            // 0..63
            float w = __shfl(ev, row, 64);         // e[row] lives in lane=row
            int idx = (row * HIDD + hq * 4) ^ ((row & 7) << 3);
            ushort4 hv = *(const ushort4*)&sH[cur][idx];
            acc4.x += w * bf2f(hv.x);
            acc4.y += w * bf2f(hv.y);
            acc4.z += w * bf2f(hv.z);
            acc4.w += w * bf2f(hv.w);
        }

        // ---- pipeline: land chunk c+1 into other half, start chunk c+2 ----
        if (c + 1 < NCH) {
            stage_write(cur ^ 1);                  // auto vmcnt on vb use
            if (c + 2 < NCH) stage_load(c + 2);
            lgk0_barrier();                        // A(c+1)
        }
    }

    // ---- epilogue: reduce 8 row-groups, write block partial ----
    *(f32x4*)&sAcc[sg][hq * 4] = acc4;
    lgk0_barrier();
    float* part = partials + (size_t)(b * BLKPB + blk) * PART_STRIDE;
    if (tid == 0) { part[0] = m_run; part[1] = l_run; }
    if (tid < 128) {
        float s = 0.f;
#pragma unroll
        for (int g = 0; g < 8; ++g) s += sAcc[g][tid];
        part[2 + tid] = s;
    }
}

// ---- combine: merge block partials, add cur_h ----
__global__ void attn_combine_kernel(const float* __restrict__ cur,
                                    const float* __restrict__ partials,
                                    float* __restrict__ out)
{
    int b = blockIdx.x, h = threadIdx.x;   // 128 threads
    const float* pb = partials + (size_t)b * BLKPB * PART_STRIDE;
    float M = -INFINITY;
    for (int c = 0; c < BLKPB; ++c) M = fmaxf(M, pb[c * PART_STRIDE]);
    float num = 0.f, den = 0.f;
    for (int c = 0; c < BLKPB; ++c) {
        float scale = __expf(pb[c * PART_STRIDE] - M);
        den += pb[c * PART_STRIDE + 1] * scale;
        num += pb[c * PART_STRIDE + 2 + h] * scale;
    }
    out[b * HIDD + h] = cur[b * HIDD + h] + num / den;
}

extern "C" void kernel_launch(void* const* d_in, const int* in_sizes, int n_in,
                              void* d_out, int out_size, void* d_ws, size_t ws_size,
                              hipStream_t stream) {
    const float* cur  = (const float*)d_in[0];
    const float* hist = (const float*)d_in[1];
    const float* wxw  = (const float*)d_in[2];
    const float* wxb  = (const float*)d_in[3];
    const float* whw  = (const float*)d_in[4];
    const float* whb  = (const float*)d_in[5];
    const float* vw   = (const float*)d_in[6];
    float* out = (float*)d_out;

    // workspace: [wbf 32KB][bias2 16KB][partials 1024*130 f32]
    unsigned short* wbf = (unsigned short*)d_ws;
    float* bias2    = (float*)((char*)d_ws + 32768);
    float* partials = (float*)((char*)d_ws + 32768 + 16384);

    prep_kernel<<<96, 256, 0, stream>>>(whw, wbf, cur, wxw, wxb, whb, bias2);
    attn_main_kernel<<<BB * BLKPB, 256, 0, stream>>>(hist, wbf, bias2, vw, partials);
    attn_combine_kernel<<<BB, HIDD, 0, stream>>>(cur, partials, out);
}

// Round 6
// 64.938 us; speedup vs baseline: 1.2596x; 1.2596x over previous
//
#include <hip/hip_runtime.h>
#include <hip/hip_bf16.h>

// Problem constants
#define BB     32
#define HIDD   128
#define ATT    128
#define SS     8192            // T*N positions per batch
#define BLKPB  32              // blocks per batch (256 rows each)
#define PART_STRIDE 132        // [m, l, pad, pad, acc[128]] (16B-aligned acc)

typedef float f32x4 __attribute__((ext_vector_type(4)));
typedef short s16x8 __attribute__((ext_vector_type(8)));

__device__ inline unsigned short f2bf(float x) {
    unsigned u = __float_as_uint(x);
    u += 0x7FFFu + ((u >> 16) & 1u);   // RNE
    return (unsigned short)(u >> 16);
}
__device__ inline float bf2f(unsigned short h) {
    return __uint_as_float(((unsigned)h) << 16);
}
__device__ inline float fast_tanh(float x) {
    x = fminf(15.f, fmaxf(-15.f, x));
    float e2 = __expf(2.f * x);
    return (e2 - 1.f) * __builtin_amdgcn_rcpf(e2 + 1.f);
}
__device__ inline unsigned cvt_pk_bf16(float a, float b) {
    unsigned r;
    asm("v_cvt_pk_bf16_f32 %0, %1, %2" : "=v"(r) : "v"(a), "v"(b));
    return r;   // low16 = bf16(a), high16 = bf16(b)
}

// ---- prep (merged): blocks 0..63 -> Wh_w f32->bf16; blocks 64..95 -> bias2 ----
__global__ void prep_kernel(const float* __restrict__ whw,
                            unsigned short* __restrict__ wbf,
                            const float* __restrict__ cur,
                            const float* __restrict__ wxw,
                            const float* __restrict__ wxb,
                            const float* __restrict__ whb,
                            float* __restrict__ bias2) {
    if (blockIdx.x < 64) {
        int i = blockIdx.x * 256 + threadIdx.x;   // 16384 total
        wbf[i] = f2bf(whw[i]);
    } else {
        __shared__ float sc[HIDD];
        int b = blockIdx.x - 64;
        int a = threadIdx.x;
        if (a < HIDD) sc[a] = cur[b * HIDD + a];
        __syncthreads();
        if (a < ATT) {
            float d = 0.f;
#pragma unroll 8
            for (int h = 0; h < HIDD; ++h) d += sc[h] * wxw[a * HIDD + h];
            bias2[b * ATT + a] = d + wxb[a] + whb[a];
        }
    }
}

// ---- main: H never touches LDS. Each wave owns 64 rows (4 tiles of 16).
//      Per tile: global->reg f32 loads (prefetched 1 tile ahead) -> cvt_pk bf16
//      frags -> swapped MFMA vs W (LDS, swizzled) -> tanh/v-dot in-lane ->
//      online softmax -> weighted accum FROM THE SAME REGS. Zero main-loop
//      barriers; block merges its 4 waves once at the end. ----
__global__ __launch_bounds__(256, 4) void attn_main_kernel(
    const float* __restrict__ hist,
    const unsigned short* __restrict__ wbf,
    const float* __restrict__ bias2,
    const float* __restrict__ vw,
    float* __restrict__ partials)
{
    __shared__ __align__(16) unsigned short sW[ATT * HIDD];  // 32 KB bf16, swizzled
    __shared__ float sB[ATT];
    __shared__ float sV[ATT];
    __shared__ float sAccW[4][HIDD];   // per-wave merged output
    __shared__ float sML[4][2];

    const int tid  = threadIdx.x;
    const int bid  = blockIdx.x;
    const int b    = bid >> 5;          // /BLKPB
    const int blk  = bid & 31;
    const int lane = tid & 63;
    const int wid  = tid >> 6;
    const int l15  = lane & 15;
    const int lg   = lane >> 4;

    // wave's 64 rows
    const float* srcw = hist + ((size_t)b * SS + (size_t)blk * 256 + wid * 64) * HIDD;

    f32x4 raw[2][8];
    auto issue = [&](int t, int buf) {   // t,buf are compile-time under unroll
        const float* r = srcw + (size_t)(t * 16 + l15) * HIDD + lg * 8;
#pragma unroll
        for (int kk = 0; kk < 4; ++kk) {
            raw[buf][2 * kk]     = *(const f32x4*)(r + kk * 32);
            raw[buf][2 * kk + 1] = *(const f32x4*)(r + kk * 32 + 4);
        }
        __builtin_amdgcn_sched_barrier(0);   // keep loads issued here
    };

    issue(0, 0);   // tile-0 loads first: HBM head start

    // ---- stage W (swizzled) + bias + v into LDS ----
#pragma unroll
    for (int i = 0; i < 8; ++i) {
        int e = (i * 256 + tid) * 8;       // u16 index
        int row = e >> 7;
        s16x8 v = *(const s16x8*)(wbf + e);
        *(s16x8*)&sW[e ^ ((row & 7) << 3)] = v;
    }
    if (tid < ATT) { sB[tid] = bias2[b * ATT + tid]; sV[tid] = vw[tid]; }
    __syncthreads();   // once per block

    float m_run = -1e30f, l_run = 0.f;
    f32x4 acc[8];
#pragma unroll
    for (int q = 0; q < 8; ++q) acc[q] = (f32x4){0.f, 0.f, 0.f, 0.f};

#pragma unroll
    for (int t = 0; t < 4; ++t) {
        const int cb = t & 1;
        // ---- cvt raw -> bf16 frags (auto-waits on this tile's loads) ----
        s16x8 hfrag[4];
#pragma unroll
        for (int kk = 0; kk < 4; ++kk) {
            union { s16x8 v; unsigned w[4]; } fr;
            fr.w[0] = cvt_pk_bf16(raw[cb][2 * kk].x,     raw[cb][2 * kk].y);
            fr.w[1] = cvt_pk_bf16(raw[cb][2 * kk].z,     raw[cb][2 * kk].w);
            fr.w[2] = cvt_pk_bf16(raw[cb][2 * kk + 1].x, raw[cb][2 * kk + 1].y);
            fr.w[3] = cvt_pk_bf16(raw[cb][2 * kk + 1].z, raw[cb][2 * kk + 1].w);
            hfrag[kk] = fr.v;
        }
        // ---- prefetch next tile (raw[cb] now free) ----
        if (t < 3) issue(t + 1, cb ^ 1);

        // ---- scores: 8 a-tiles, D[a][s] = W . H^T, v-dot in-lane ----
        float p = 0.f;
#pragma unroll
        for (int at = 0; at < 8; ++at) {
            s16x8 wfrag[4];
#pragma unroll
            for (int kk = 0; kk < 4; ++kk) {
                int idx = ((at * 16 + l15) * HIDD + kk * 32 + lg * 8) ^ ((l15 & 7) << 3);
                wfrag[kk] = *(const s16x8*)&sW[idx];
            }
            f32x4 d = {0.f, 0.f, 0.f, 0.f};
#pragma unroll
            for (int kk = 0; kk < 4; ++kk)
                d = __builtin_amdgcn_mfma_f32_16x16x32_bf16(wfrag[kk], hfrag[kk], d, 0, 0, 0);
            f32x4 bb = *(const f32x4*)&sB[at * 16 + lg * 4];
            f32x4 vx = *(const f32x4*)&sV[at * 16 + lg * 4];
#pragma unroll
            for (int r = 0; r < 4; ++r)
                p += vx[r] * fast_tanh(d[r] + bb[r]);
        }
        p += __shfl_xor(p, 16, 64);
        p += __shfl_xor(p, 32, 64);   // all lanes: score for s = (tile row l15)

        // ---- online softmax over this tile's 16 rows ----
        float mx = p;
#pragma unroll
        for (int m = 1; m < 16; m <<= 1) mx = fmaxf(mx, __shfl_xor(mx, m, 64));
        float m_new = fmaxf(m_run, mx);
        float so = __expf(m_run - m_new);
        float ev = __expf(p - m_new);
        float es = ev;
#pragma unroll
        for (int m = 1; m < 16; m <<= 1) es += __shfl_xor(es, m, 64);
        l_run = l_run * so + es;
        m_run = m_new;

        // ---- weighted accumulation from the SAME frags (H touched once) ----
#pragma unroll
        for (int q = 0; q < 8; ++q) acc[q] *= so;
#pragma unroll
        for (int kk = 0; kk < 4; ++kk) {
            union { s16x8 v; unsigned short u[8]; } fr; fr.v = hfrag[kk];
#pragma unroll
            for (int i = 0; i < 4; ++i) acc[2 * kk][i]     += ev * bf2f(fr.u[i]);
#pragma unroll
            for (int i = 0; i < 4; ++i) acc[2 * kk + 1][i] += ev * bf2f(fr.u[4 + i]);
        }
    }

    // ---- reduce acc over the 16 s-lanes (l15) ----
#pragma unroll
    for (int m = 1; m < 16; m <<= 1) {
#pragma unroll
        for (int q = 0; q < 8; ++q) {
#pragma unroll
            for (int i = 0; i < 4; ++i)
                acc[q][i] += __shfl_xor(acc[q][i], m, 64);
        }
    }
    // lanes l15==0 (lg = 0..3) hold h[k] for k = kk*32 + lg*8 + i
    if (l15 == 0) {
#pragma unroll
        for (int kk = 0; kk < 4; ++kk) {
            *(f32x4*)&sAccW[wid][kk * 32 + lg * 8]     = acc[2 * kk];
            *(f32x4*)&sAccW[wid][kk * 32 + lg * 8 + 4] = acc[2 * kk + 1];
        }
    }
    if (lane == 0) { sML[wid][0] = m_run; sML[wid][1] = l_run; }
    __syncthreads();

    // ---- merge 4 waves, one partial per block ----
    if (tid < HIDD) {
        float M = fmaxf(fmaxf(sML[0][0], sML[1][0]), fmaxf(sML[2][0], sML[3][0]));
        float num = 0.f, den = 0.f;
#pragma unroll
        for (int w = 0; w < 4; ++w) {
            float sc = __expf(sML[w][0] - M);
            den += sML[w][1] * sc;
            num += sAccW[w][tid] * sc;
        }
        float* part = partials + (size_t)(b * BLKPB + blk) * PART_STRIDE;
        part[4 + tid] = num;
        if (tid == 0) { part[0] = M; part[1] = den; }
    }
}

// ---- combine: merge block partials, add cur_h ----
__global__ void attn_combine_kernel(const float* __restrict__ cur,
                                    const float* __restrict__ partials,
                                    float* __restrict__ out)
{
    int b = blockIdx.x, h = threadIdx.x;   // 128 threads
    const float* pb = partials + (size_t)b * BLKPB * PART_STRIDE;
    float M = -INFINITY;
    for (int c = 0; c < BLKPB; ++c) M = fmaxf(M, pb[c * PART_STRIDE]);
    float num = 0.f, den = 0.f;
    for (int c = 0; c < BLKPB; ++c) {
        float scale = __expf(pb[c * PART_STRIDE] - M);
        den += pb[c * PART_STRIDE + 1] * scale;
        num += pb[c * PART_STRIDE + 4 + h] * scale;
    }
    out[b * HIDD + h] = cur[b * HIDD + h] + num / den;
}

extern "C" void kernel_launch(void* const* d_in, const int* in_sizes, int n_in,
                              void* d_out, int out_size, void* d_ws, size_t ws_size,
                              hipStream_t stream) {
    const float* cur  = (const float*)d_in[0];
    const float* hist = (const float*)d_in[1];
    const float* wxw  = (const float*)d_in[2];
    const float* wxb  = (const float*)d_in[3];
    const float* whw  = (const float*)d_in[4];
    const float* whb  = (const float*)d_in[5];
    const float* vw   = (const float*)d_in[6];
    float* out = (float*)d_out;

    // workspace: [wbf 32KB][bias2 16KB][partials 1024*132 f32 ~ 540KB]
    unsigned short* wbf = (unsigned short*)d_ws;
    float* bias2    = (float*)((char*)d_ws + 32768);
    float* partials = (float*)((char*)d_ws + 32768 + 16384);

    prep_kernel<<<96, 256, 0, stream>>>(whw, wbf, cur, wxw, wxb, whb, bias2);
    attn_main_kernel<<<BB * BLKPB, 256, 0, stream>>>(hist, wbf, bias2, vw, partials);
    attn_combine_kernel<<<BB, HIDD, 0, stream>>>(cur, partials, out);
}

// Round 7
// 64.702 us; speedup vs baseline: 1.2642x; 1.0036x over previous
//
#include <hip/hip_runtime.h>
#include <hip/hip_bf16.h>

// Problem constants
#define BB     32
#define HIDD   128
#define ATT    128
#define SS     8192            // T*N positions per batch
#define BLKPB  32              // blocks per batch (256 rows each)
#define PART_STRIDE 132        // [m, l, pad, pad, acc[128]] (16B-aligned acc)

typedef float f32x4 __attribute__((ext_vector_type(4)));
typedef short s16x8 __attribute__((ext_vector_type(8)));

__device__ inline unsigned short f2bf(float x) {
    unsigned u = __float_as_uint(x);
    u += 0x7FFFu + ((u >> 16) & 1u);   // RNE
    return (unsigned short)(u >> 16);
}
__device__ inline float bf2f(unsigned short h) {
    return __uint_as_float(((unsigned)h) << 16);
}
__device__ inline float fast_tanh(float x) {
    x = fminf(15.f, fmaxf(-15.f, x));
    float e2 = __expf(2.f * x);
    return (e2 - 1.f) * __builtin_amdgcn_rcpf(e2 + 1.f);
}
__device__ inline unsigned cvt_pk_bf16(float a, float b) {
    unsigned r;
    asm("v_cvt_pk_bf16_f32 %0, %1, %2" : "=v"(r) : "v"(a), "v"(b));
    return r;   // low16 = bf16(a), high16 = bf16(b)
}

// ---- prep (merged): blocks 0..63 -> Wh_w f32->bf16; blocks 64..95 -> bias2 ----
__global__ void prep_kernel(const float* __restrict__ whw,
                            unsigned short* __restrict__ wbf,
                            const float* __restrict__ cur,
                            const float* __restrict__ wxw,
                            const float* __restrict__ wxb,
                            const float* __restrict__ whb,
                            float* __restrict__ bias2) {
    if (blockIdx.x < 64) {
        int i = blockIdx.x * 256 + threadIdx.x;   // 16384 total
        wbf[i] = f2bf(whw[i]);
    } else {
        __shared__ float sc[HIDD];
        int b = blockIdx.x - 64;
        int a = threadIdx.x;
        if (a < HIDD) sc[a] = cur[b * HIDD + a];
        __syncthreads();
        if (a < ATT) {
            float d = 0.f;
#pragma unroll 8
            for (int h = 0; h < HIDD; ++h) d += sc[h] * wxw[a * HIDD + h];
            bias2[b * ATT + a] = d + wxb[a] + whb[a];
        }
    }
}

// ---- main: H never touches LDS. Each wave owns 64 rows (4 tiles of 16).
//      SINGLE raw[8] prefetch buffer, no parity indexing (rule #20: parity-
//      indexed ext_vector arrays spill to scratch). Per tile: cvt raw->hfrag,
//      re-issue next tile's loads into raw (async), MFMA vs W (LDS) hides the
//      latency. Weighted accum from the same hfrag regs. Zero main-loop
//      barriers; 4 waves merge once at the end. ----
__global__ __launch_bounds__(256, 4) void attn_main_kernel(
    const float* __restrict__ hist,
    const unsigned short* __restrict__ wbf,
    const float* __restrict__ bias2,
    const float* __restrict__ vw,
    float* __restrict__ partials)
{
    __shared__ __align__(16) unsigned short sW[ATT * HIDD];  // 32 KB bf16, swizzled
    __shared__ float sB[ATT];
    __shared__ float sV[ATT];
    __shared__ float sAccW[4][HIDD];   // per-wave merged output
    __shared__ float sML[4][2];

    const int tid  = threadIdx.x;
    const int bid  = blockIdx.x;
    const int b    = bid >> 5;          // /BLKPB
    const int blk  = bid & 31;
    const int lane = tid & 63;
    const int wid  = tid >> 6;
    const int l15  = lane & 15;
    const int lg   = lane >> 4;

    // wave's 64 rows
    const float* srcw = hist + ((size_t)b * SS + (size_t)blk * 256 + wid * 64) * HIDD;

    f32x4 raw[8];   // single in-flight tile (16 rows x 128 f32 / 64 lanes)
    auto issue = [&](int t) {
        const float* r = srcw + (size_t)(t * 16 + l15) * HIDD + lg * 8;
#pragma unroll
        for (int kk = 0; kk < 4; ++kk) {
            raw[2 * kk]     = *(const f32x4*)(r + kk * 32);
            raw[2 * kk + 1] = *(const f32x4*)(r + kk * 32 + 4);
        }
        __builtin_amdgcn_sched_barrier(0);   // pin issue point
    };

    issue(0);   // tile-0 loads first: HBM head start

    // ---- stage W (swizzled) + bias + v into LDS ----
#pragma unroll
    for (int i = 0; i < 8; ++i) {
        int e = (i * 256 + tid) * 8;       // u16 index
        int row = e >> 7;
        s16x8 v = *(const s16x8*)(wbf + e);
        *(s16x8*)&sW[e ^ ((row & 7) << 3)] = v;
    }
    if (tid < ATT) { sB[tid] = bias2[b * ATT + tid]; sV[tid] = vw[tid]; }
    __syncthreads();   // once per block

    float m_run = -1e30f, l_run = 0.f;
    f32x4 acc[8];
#pragma unroll
    for (int q = 0; q < 8; ++q) acc[q] = (f32x4){0.f, 0.f, 0.f, 0.f};

#pragma unroll
    for (int t = 0; t < 4; ++t) {
        // ---- cvt raw -> bf16 frags (auto-waits this tile's loads) ----
        s16x8 hfrag[4];
#pragma unroll
        for (int kk = 0; kk < 4; ++kk) {
            union { s16x8 v; unsigned w[4]; } fr;
            fr.w[0] = cvt_pk_bf16(raw[2 * kk].x,     raw[2 * kk].y);
            fr.w[1] = cvt_pk_bf16(raw[2 * kk].z,     raw[2 * kk].w);
            fr.w[2] = cvt_pk_bf16(raw[2 * kk + 1].x, raw[2 * kk + 1].y);
            fr.w[3] = cvt_pk_bf16(raw[2 * kk + 1].z, raw[2 * kk + 1].w);
            hfrag[kk] = fr.v;
        }
        // ---- re-issue next tile into the SAME raw regs (async) ----
        if (t < 3) issue(t + 1);

        // ---- scores: 8 a-tiles, D[a][s] = W . H^T, v-dot in-lane ----
        float p = 0.f;
#pragma unroll
        for (int at = 0; at < 8; ++at) {
            s16x8 wfrag[4];
#pragma unroll
            for (int kk = 0; kk < 4; ++kk) {
                int idx = ((at * 16 + l15) * HIDD + kk * 32 + lg * 8) ^ ((l15 & 7) << 3);
                wfrag[kk] = *(const s16x8*)&sW[idx];
            }
            f32x4 d = {0.f, 0.f, 0.f, 0.f};
#pragma unroll
            for (int kk = 0; kk < 4; ++kk)
                d = __builtin_amdgcn_mfma_f32_16x16x32_bf16(wfrag[kk], hfrag[kk], d, 0, 0, 0);
            f32x4 bb = *(const f32x4*)&sB[at * 16 + lg * 4];
            f32x4 vx = *(const f32x4*)&sV[at * 16 + lg * 4];
#pragma unroll
            for (int r = 0; r < 4; ++r)
                p += vx[r] * fast_tanh(d[r] + bb[r]);
        }
        p += __shfl_xor(p, 16, 64);
        p += __shfl_xor(p, 32, 64);   // all lanes: score for row = l15

        // ---- online softmax over this tile's 16 rows ----
        float mx = p;
#pragma unroll
        for (int m = 1; m < 16; m <<= 1) mx = fmaxf(mx, __shfl_xor(mx, m, 64));
        float m_new = fmaxf(m_run, mx);
        float so = __expf(m_run - m_new);
        float ev = __expf(p - m_new);
        float es = ev;
#pragma unroll
        for (int m = 1; m < 16; m <<= 1) es += __shfl_xor(es, m, 64);
        l_run = l_run * so + es;
        m_run = m_new;

        // ---- weighted accumulation from the SAME frags (H touched once) ----
#pragma unroll
        for (int q = 0; q < 8; ++q) acc[q] *= so;
#pragma unroll
        for (int kk = 0; kk < 4; ++kk) {
            union { s16x8 v; unsigned short u[8]; } fr; fr.v = hfrag[kk];
#pragma unroll
            for (int i = 0; i < 4; ++i) acc[2 * kk][i]     += ev * bf2f(fr.u[i]);
#pragma unroll
            for (int i = 0; i < 4; ++i) acc[2 * kk + 1][i] += ev * bf2f(fr.u[4 + i]);
        }
    }

    // ---- reduce acc over the 16 s-lanes (within each 16-lane group) ----
#pragma unroll
    for (int m = 1; m < 16; m <<= 1) {
#pragma unroll
        for (int q = 0; q < 8; ++q) {
#pragma unroll
            for (int i = 0; i < 4; ++i)
                acc[q][i] += __shfl_xor(acc[q][i], m, 64);
        }
    }
    // lanes l15==0 (lg = 0..3) hold h[k] for k = kk*32 + lg*8 + i
    if (l15 == 0) {
#pragma unroll
        for (int kk = 0; kk < 4; ++kk) {
            *(f32x4*)&sAccW[wid][kk * 32 + lg * 8]     = acc[2 * kk];
            *(f32x4*)&sAccW[wid][kk * 32 + lg * 8 + 4] = acc[2 * kk + 1];
        }
    }
    if (lane == 0) { sML[wid][0] = m_run; sML[wid][1] = l_run; }
    __syncthreads();

    // ---- merge 4 waves, one partial per block ----
    if (tid < HIDD) {
        float M = fmaxf(fmaxf(sML[0][0], sML[1][0]), fmaxf(sML[2][0], sML[3][0]));
        float num = 0.f, den = 0.f;
#pragma unroll
        for (int w = 0; w < 4; ++w) {
            float sc = __expf(sML[w][0] - M);
            den += sML[w][1] * sc;
            num += sAccW[w][tid] * sc;
        }
        float* part = partials + (size_t)(b * BLKPB + blk) * PART_STRIDE;
        part[4 + tid] = num;
        if (tid == 0) { part[0] = M; part[1] = den; }
    }
}

// ---- combine: merge block partials, add cur_h ----
__global__ void attn_combine_kernel(const float* __restrict__ cur,
                                    const float* __restrict__ partials,
                                    float* __restrict__ out)
{
    int b = blockIdx.x, h = threadIdx.x;   // 128 threads
    const float* pb = partials + (size_t)b * BLKPB * PART_STRIDE;
    float M = -INFINITY;
    for (int c = 0; c < BLKPB; ++c) M = fmaxf(M, pb[c * PART_STRIDE]);
    float num = 0.f, den = 0.f;
    for (int c = 0; c < BLKPB; ++c) {
        float scale = __expf(pb[c * PART_STRIDE] - M);
        den += pb[c * PART_STRIDE + 1] * scale;
        num += pb[c * PART_STRIDE + 4 + h] * scale;
    }
    out[b * HIDD + h] = cur[b * HIDD + h] + num / den;
}

extern "C" void kernel_launch(void* const* d_in, const int* in_sizes, int n_in,
                              void* d_out, int out_size, void* d_ws, size_t ws_size,
                              hipStream_t stream) {
    const float* cur  = (const float*)d_in[0];
    const float* hist = (const float*)d_in[1];
    const float* wxw  = (const float*)d_in[2];
    const float* wxb  = (const float*)d_in[3];
    const float* whw  = (const float*)d_in[4];
    const float* whb  = (const float*)d_in[5];
    const float* vw   = (const float*)d_in[6];
    float* out = (float*)d_out;

    // workspace: [wbf 32KB][bias2 16KB][partials 1024*132 f32 ~ 540KB]
    unsigned short* wbf = (unsigned short*)d_ws;
    float* bias2    = (float*)((char*)d_ws + 32768);
    float* partials = (float*)((char*)d_ws + 32768 + 16384);

    prep_kernel<<<96, 256, 0, stream>>>(whw, wbf, cur, wxw, wxb, whb, bias2);
    attn_main_kernel<<<BB * BLKPB, 256, 0, stream>>>(hist, wbf, bias2, vw, partials);
    attn_combine_kernel<<<BB, HIDD, 0, stream>>>(cur, partials, out);
}

// Round 8
// 47.169 us; speedup vs baseline: 1.7341x; 1.3717x over previous
//
#include <hip/hip_runtime.h>
#include <hip/hip_bf16.h>

// Problem constants
#define BB     32
#define HIDD   128
#define ATT    128
#define SS     8192            // T*N positions per batch
#define BLKPB  32              // blocks per batch (256 rows each)
#define PART_STRIDE 132        // [m, l, pad, pad, acc[128]] (16B-aligned acc)

typedef float f32x4 __attribute__((ext_vector_type(4)));
typedef short s16x8 __attribute__((ext_vector_type(8)));

__device__ inline unsigned short f2bf(float x) {
    unsigned u = __float_as_uint(x);
    u += 0x7FFFu + ((u >> 16) & 1u);   // RNE
    return (unsigned short)(u >> 16);
}
__device__ inline float bf2f(unsigned short h) {
    return __uint_as_float(((unsigned)h) << 16);
}
__device__ inline float fast_tanh(float x) {
    x = fminf(15.f, fmaxf(-15.f, x));
    float e2 = __expf(2.f * x);
    return (e2 - 1.f) * __builtin_amdgcn_rcpf(e2 + 1.f);
}
__device__ inline unsigned cvt_pk_bf16(float a, float b) {
    unsigned r;
    asm("v_cvt_pk_bf16_f32 %0, %1, %2" : "=v"(r) : "v"(a), "v"(b));
    return r;   // low16 = bf16(a), high16 = bf16(b)
}

// ---- prep (merged): blocks 0..63 -> Wh_w f32->bf16; blocks 64..95 -> bias2 ----
__global__ void prep_kernel(const float* __restrict__ whw,
                            unsigned short* __restrict__ wbf,
                            const float* __restrict__ cur,
                            const float* __restrict__ wxw,
                            const float* __restrict__ wxb,
                            const float* __restrict__ whb,
                            float* __restrict__ bias2) {
    if (blockIdx.x < 64) {
        int i = blockIdx.x * 256 + threadIdx.x;   // 16384 total
        wbf[i] = f2bf(whw[i]);
    } else {
        __shared__ float sc[HIDD];
        int b = blockIdx.x - 64;
        int a = threadIdx.x;
        if (a < HIDD) sc[a] = cur[b * HIDD + a];
        __syncthreads();
        if (a < ATT) {
            float d = 0.f;
#pragma unroll 8
            for (int h = 0; h < HIDD; ++h) d += sc[h] * wxw[a * HIDD + h];
            bias2[b * ATT + a] = d + wxb[a] + whb[a];
        }
    }
}

// ---- main: H never touches LDS. Each wave owns 64 rows (4 tiles of 16).
//      Single raw[8] prefetch buffer; per tile: cvt raw->hfrag, re-issue next
//      tile's loads into raw (async), MFMA vs W (LDS) hides the latency.
//      Weighted accum from the same hfrag regs. Zero main-loop barriers.
//      NOTE __launch_bounds__(256, 2): empirically the 2nd arg's VGPR cap is
//      256/arg on this backend (R4: arg2->128, R5-7: arg4->64+spill). arg=2
//      gives cap 128; actual ~120 still yields 16 waves/CU. ----
__global__ __launch_bounds__(256, 2) void attn_main_kernel(
    const float* __restrict__ hist,
    const unsigned short* __restrict__ wbf,
    const float* __restrict__ bias2,
    const float* __restrict__ vw,
    float* __restrict__ partials)
{
    __shared__ __align__(16) unsigned short sW[ATT * HIDD];  // 32 KB bf16, swizzled
    __shared__ float sB[ATT];
    __shared__ float sV[ATT];
    __shared__ float sAccW[4][HIDD];   // per-wave merged output
    __shared__ float sML[4][2];

    const int tid  = threadIdx.x;
    const int bid  = blockIdx.x;
    const int b    = bid >> 5;          // /BLKPB
    const int blk  = bid & 31;
    const int lane = tid & 63;
    const int wid  = tid >> 6;
    const int l15  = lane & 15;
    const int lg   = lane >> 4;

    // wave's 64 rows
    const float* srcw = hist + ((size_t)b * SS + (size_t)blk * 256 + wid * 64) * HIDD;

    f32x4 raw[8];   // single in-flight tile (16 rows x 128 f32 / 64 lanes)
    auto issue = [&](int t) {
        const float* r = srcw + (size_t)(t * 16 + l15) * HIDD + lg * 8;
#pragma unroll
        for (int kk = 0; kk < 4; ++kk) {
            raw[2 * kk]     = *(const f32x4*)(r + kk * 32);
            raw[2 * kk + 1] = *(const f32x4*)(r + kk * 32 + 4);
        }
        __builtin_amdgcn_sched_barrier(0);   // pin issue point
    };

    issue(0);   // tile-0 loads first: HBM head start

    // ---- stage W (swizzled) + bias + v into LDS ----
#pragma unroll
    for (int i = 0; i < 8; ++i) {
        int e = (i * 256 + tid) * 8;       // u16 index
        int row = e >> 7;
        s16x8 v = *(const s16x8*)(wbf + e);
        *(s16x8*)&sW[e ^ ((row & 7) << 3)] = v;
    }
    if (tid < ATT) { sB[tid] = bias2[b * ATT + tid]; sV[tid] = vw[tid]; }
    __syncthreads();   // once per block

    float m_run = -1e30f, l_run = 0.f;
    f32x4 acc[8];
#pragma unroll
    for (int q = 0; q < 8; ++q) acc[q] = (f32x4){0.f, 0.f, 0.f, 0.f};

#pragma unroll
    for (int t = 0; t < 4; ++t) {
        // ---- cvt raw -> bf16 frags (auto-waits this tile's loads) ----
        s16x8 hfrag[4];
#pragma unroll
        for (int kk = 0; kk < 4; ++kk) {
            union { s16x8 v; unsigned w[4]; } fr;
            fr.w[0] = cvt_pk_bf16(raw[2 * kk].x,     raw[2 * kk].y);
            fr.w[1] = cvt_pk_bf16(raw[2 * kk].z,     raw[2 * kk].w);
            fr.w[2] = cvt_pk_bf16(raw[2 * kk + 1].x, raw[2 * kk + 1].y);
            fr.w[3] = cvt_pk_bf16(raw[2 * kk + 1].z, raw[2 * kk + 1].w);
            hfrag[kk] = fr.v;
        }
        // ---- re-issue next tile into the SAME raw regs (async) ----
        if (t < 3) issue(t + 1);

        // ---- scores: 8 a-tiles, D[a][s] = W . H^T, v-dot in-lane ----
        float p = 0.f;
#pragma unroll
        for (int at = 0; at < 8; ++at) {
            s16x8 wfrag[4];
#pragma unroll
            for (int kk = 0; kk < 4; ++kk) {
                int idx = ((at * 16 + l15) * HIDD + kk * 32 + lg * 8) ^ ((l15 & 7) << 3);
                wfrag[kk] = *(const s16x8*)&sW[idx];
            }
            f32x4 d = {0.f, 0.f, 0.f, 0.f};
#pragma unroll
            for (int kk = 0; kk < 4; ++kk)
                d = __builtin_amdgcn_mfma_f32_16x16x32_bf16(wfrag[kk], hfrag[kk], d, 0, 0, 0);
            f32x4 bb = *(const f32x4*)&sB[at * 16 + lg * 4];
            f32x4 vx = *(const f32x4*)&sV[at * 16 + lg * 4];
#pragma unroll
            for (int r = 0; r < 4; ++r)
                p += vx[r] * fast_tanh(d[r] + bb[r]);
        }
        p += __shfl_xor(p, 16, 64);
        p += __shfl_xor(p, 32, 64);   // all lanes: score for row = l15

        // ---- online softmax over this tile's 16 rows ----
        float mx = p;
#pragma unroll
        for (int m = 1; m < 16; m <<= 1) mx = fmaxf(mx, __shfl_xor(mx, m, 64));
        float m_new = fmaxf(m_run, mx);
        float so = __expf(m_run - m_new);
        float ev = __expf(p - m_new);
        float es = ev;
#pragma unroll
        for (int m = 1; m < 16; m <<= 1) es += __shfl_xor(es, m, 64);
        l_run = l_run * so + es;
        m_run = m_new;

        // ---- weighted accumulation from the SAME frags (H touched once) ----
#pragma unroll
        for (int q = 0; q < 8; ++q) acc[q] *= so;
#pragma unroll
        for (int kk = 0; kk < 4; ++kk) {
            union { s16x8 v; unsigned short u[8]; } fr; fr.v = hfrag[kk];
#pragma unroll
            for (int i = 0; i < 4; ++i) acc[2 * kk][i]     += ev * bf2f(fr.u[i]);
#pragma unroll
            for (int i = 0; i < 4; ++i) acc[2 * kk + 1][i] += ev * bf2f(fr.u[4 + i]);
        }
    }

    // ---- reduce acc over the 16 s-lanes (within each 16-lane group) ----
#pragma unroll
    for (int m = 1; m < 16; m <<= 1) {
#pragma unroll
        for (int q = 0; q < 8; ++q) {
#pragma unroll
            for (int i = 0; i < 4; ++i)
                acc[q][i] += __shfl_xor(acc[q][i], m, 64);
        }
    }
    // lanes l15==0 (lg = 0..3) hold h[k] for k = kk*32 + lg*8 + i
    if (l15 == 0) {
#pragma unroll
        for (int kk = 0; kk < 4; ++kk) {
            *(f32x4*)&sAccW[wid][kk * 32 + lg * 8]     = acc[2 * kk];
            *(f32x4*)&sAccW[wid][kk * 32 + lg * 8 + 4] = acc[2 * kk + 1];
        }
    }
    if (lane == 0) { sML[wid][0] = m_run; sML[wid][1] = l_run; }
    __syncthreads();

    // ---- merge 4 waves, one partial per block ----
    if (tid < HIDD) {
        float M = fmaxf(fmaxf(sML[0][0], sML[1][0]), fmaxf(sML[2][0], sML[3][0]));
        float num = 0.f, den = 0.f;
#pragma unroll
        for (int w = 0; w < 4; ++w) {
            float sc = __expf(sML[w][0] - M);
            den += sML[w][1] * sc;
            num += sAccW[w][tid] * sc;
        }
        float* part = partials + (size_t)(b * BLKPB + blk) * PART_STRIDE;
        part[4 + tid] = num;
        if (tid == 0) { part[0] = M; part[1] = den; }
    }
}

// ---- combine: merge block partials, add cur_h ----
__global__ void attn_combine_kernel(const float* __restrict__ cur,
                                    const float* __restrict__ partials,
                                    float* __restrict__ out)
{
    int b = blockIdx.x, h = threadIdx.x;   // 128 threads
    const float* pb = partials + (size_t)b * BLKPB * PART_STRIDE;
    float M = -INFINITY;
    for (int c = 0; c < BLKPB; ++c) M = fmaxf(M, pb[c * PART_STRIDE]);
    float num = 0.f, den = 0.f;
    for (int c = 0; c < BLKPB; ++c) {
        float scale = __expf(pb[c * PART_STRIDE] - M);
        den += pb[c * PART_STRIDE + 1] * scale;
        num += pb[c * PART_STRIDE + 4 + h] * scale;
    }
    out[b * HIDD + h] = cur[b * HIDD + h] + num / den;
}

extern "C" void kernel_launch(void* const* d_in, const int* in_sizes, int n_in,
                              void* d_out, int out_size, void* d_ws, size_t ws_size,
                              hipStream_t stream) {
    const float* cur  = (const float*)d_in[0];
    const float* hist = (const float*)d_in[1];
    const float* wxw  = (const float*)d_in[2];
    const float* wxb  = (const float*)d_in[3];
    const float* whw  = (const float*)d_in[4];
    const float* whb  = (const float*)d_in[5];
    const float* vw   = (const float*)d_in[6];
    float* out = (float*)d_out;

    // workspace: [wbf 32KB][bias2 16KB][partials 1024*132 f32 ~ 540KB]
    unsigned short* wbf = (unsigned short*)d_ws;
    float* bias2    = (float*)((char*)d_ws + 32768);
    float* partials = (float*)((char*)d_ws + 32768 + 16384);

    prep_kernel<<<96, 256, 0, stream>>>(whw, wbf, cur, wxw, wxb, whb, bias2);
    attn_main_kernel<<<BB * BLKPB, 256, 0, stream>>>(hist, wbf, bias2, vw, partials);
    attn_combine_kernel<<<BB, HIDD, 0, stream>>>(cur, partials, out);
}